// Round 2
// baseline (364.605 us; speedup 1.0000x reference)
//
#include <hip/hip_runtime.h>
#include <hip/hip_bf16.h>
#include <stdint.h>

// ---------------- problem geometry ----------------
constexpr int L  = 2048;
constexpr int NB = 4;                 // batch
constexpr int E  = 1024;
constexpr int H  = 16;
constexpr int DH = 64;
constexpr int M  = L * NB;            // 8192 tokens
constexpr int K  = E;                 // 1024 (GEMM inner dim)
constexpr int QKV_LD = 3 * E;         // 3072

typedef float  f32x4  __attribute__((ext_vector_type(4)));
typedef __bf16 bf16x4 __attribute__((ext_vector_type(4)));
typedef __bf16 bf16x8 __attribute__((ext_vector_type(8)));

#define AS1 __attribute__((address_space(1)))
#define AS3 __attribute__((address_space(3)))

static __device__ __forceinline__ void gl_lds16(const void* g, void* l) {
  __builtin_amdgcn_global_load_lds((const AS1 uint32_t*)g, (AS3 uint32_t*)l, 16, 0, 0);
}

// =====================================================================
// fp32 -> bf16 bulk convert (device buffers are fp32 per npz sizes)
// =====================================================================
__global__ __launch_bounds__(256)
void cvt_f32_bf16(const float* __restrict__ in, __bf16* __restrict__ out, int n4) {
  const int i = blockIdx.x * blockDim.x + threadIdx.x;
  if (i < n4) {
    const f32x4 v = ((const f32x4*)in)[i];
    bf16x4 o;
#pragma unroll
    for (int j = 0; j < 4; j++) o[j] = (__bf16)v[j];
    ((bf16x4*)out)[i] = o;
  }
}

// =====================================================================
// GEMM: C[M][NC] = A[M][K] * B[NC][K]^T   (bf16 in, fp32 accum, OutT out)
// 128x128 tile, BK=64, 4 waves (2x2 of 64x64), 16x16x32 bf16 MFMA.
// LDS tiles XOR-swizzled (byte ^= (row&7)<<4) via pre-swizzled global src.
// =====================================================================
template<int NC, typename OutT>
__global__ __launch_bounds__(256)
void gemm_bt(const __bf16* __restrict__ A, const __bf16* __restrict__ B,
             OutT* __restrict__ C) {
  constexpr int BK = 64;
  __shared__ char lds[2 * 128 * BK * 2];          // A tile 16KB, B tile 16KB
  char* aL = lds;
  char* bL = lds + 128 * BK * 2;

  const int t    = threadIdx.x;
  const int lane = t & 63;
  const int w    = t >> 6;          // wave 0..3
  const int g    = lane >> 4;       // 0..3
  const int c    = lane & 15;

  const int rowBase = blockIdx.y * 128;
  const int colBase = blockIdx.x * 128;

  // staging: 4 issues of 16B per thread per matrix; dest linear, src swizzled
  const int srow = t >> 3;                         // 0..31 (row within 32-row chunk)
  const int scb  = (t & 7) * 16;                   // byte col within 128B row
  const int ssw  = scb ^ ((srow & 7) << 4);        // pre-swizzled source byte

  const char* aSrcBase = (const char*)(A + (size_t)(rowBase + srow) * K) + ssw;
  const char* bSrcBase = (const char*)(B + (size_t)(colBase + srow) * K) + ssw;

  f32x4 acc[4][4];
#pragma unroll
  for (int i = 0; i < 4; i++)
#pragma unroll
    for (int j = 0; j < 4; j++) acc[i][j] = f32x4{0.f, 0.f, 0.f, 0.f};

  const int wr = (w >> 1) * 64;
  const int wc = (w & 1) * 64;

  for (int k0 = 0; k0 < K; k0 += BK) {
    __syncthreads();                               // compute of prev tile done
#pragma unroll
    for (int q = 0; q < 4; q++) {
      gl_lds16(aSrcBase + (size_t)2 * k0 + (size_t)q * 32 * K * 2, aL + q * 4096 + t * 16);
      gl_lds16(bSrcBase + (size_t)2 * k0 + (size_t)q * 32 * K * 2, bL + q * 4096 + t * 16);
    }
    __syncthreads();                               // barrier drains vmcnt

    bf16x8 af[4][2], bfR[4][2];
#pragma unroll
    for (int mi = 0; mi < 4; mi++) {
      const int row = wr + mi * 16 + c;
      const int sw  = (row & 7) << 4;
#pragma unroll
      for (int ks = 0; ks < 2; ks++)
        af[mi][ks] = *(const bf16x8*)(aL + row * 128 + ((ks * 64 + g * 16) ^ sw));
    }
#pragma unroll
    for (int ni = 0; ni < 4; ni++) {
      const int row = wc + ni * 16 + c;
      const int sw  = (row & 7) << 4;
#pragma unroll
      for (int ks = 0; ks < 2; ks++)
        bfR[ni][ks] = *(const bf16x8*)(bL + row * 128 + ((ks * 64 + g * 16) ^ sw));
    }
#pragma unroll
    for (int mi = 0; mi < 4; mi++)
#pragma unroll
      for (int ni = 0; ni < 4; ni++)
#pragma unroll
        for (int ks = 0; ks < 2; ks++)
          acc[mi][ni] = __builtin_amdgcn_mfma_f32_16x16x32_bf16(
              af[mi][ks], bfR[ni][ks], acc[mi][ni], 0, 0, 0);
  }

  // epilogue: C/D layout col = lane&15, row = (lane>>4)*4 + reg
#pragma unroll
  for (int mi = 0; mi < 4; mi++)
#pragma unroll
    for (int ni = 0; ni < 4; ni++)
#pragma unroll
      for (int r = 0; r < 4; r++) {
        const int row = rowBase + wr + mi * 16 + g * 4 + r;
        const int col = colBase + wc + ni * 16 + c;
        C[(size_t)row * NC + col] = (OutT)acc[mi][ni][r];
      }
}

// =====================================================================
// Causal flash attention over qkv buffer [M][3072]
//   q at col h*64, k at 1024+h*64, v at 2048+h*64, token row = l*4+n
// grid (32, 64): x -> q-tile (reversed for load balance), y -> b = n*16+h
// block 256 = 4 waves; wave w owns q rows qt*64+w*16 .. +15
// =====================================================================
__global__ __launch_bounds__(256)
void attn_kernel(const __bf16* __restrict__ qkv, __bf16* __restrict__ out) {
  const int qt = 31 - (int)blockIdx.x;
  const int b  = blockIdx.y;
  const int n  = b >> 4;
  const int h  = b & 15;

  __shared__ char kl[64 * 128];       // K tile [kv][d], swizzled (row&7)<<4
  __shared__ char vt[64 * 128];       // V^T   [d][kv], swizzled ((d&7)^(d>>3))<<4
  __shared__ char pl[4][16 * 128];    // per-wave P [q16][kv64], swizzled (row&7)<<4

  const int t    = threadIdx.x;
  const int lane = t & 63;
  const int w    = t >> 6;
  const int g    = lane >> 4;
  const int c    = lane & 15;

  // Q fragments in registers: A[row=c][k = ks*32 + g*8 + i]
  bf16x8 qa[2];
  {
    const int qrow = qt * 64 + w * 16 + c;
    const __bf16* qp = qkv + (size_t)(qrow * 4 + n) * QKV_LD + h * 64;
    qa[0] = *(const bf16x8*)(qp + g * 8);
    qa[1] = *(const bf16x8*)(qp + 32 + g * 8);
  }

  float mrow[4], lrow[4];
  f32x4 o[4];
#pragma unroll
  for (int r = 0; r < 4; r++) { mrow[r] = -3e38f; lrow[r] = 0.f; }
#pragma unroll
  for (int ni = 0; ni < 4; ni++) o[ni] = f32x4{0.f, 0.f, 0.f, 0.f};

  const int srow = t >> 3;            // 0..31
  const int scb  = (t & 7) * 16;
  const int kssw = scb ^ ((srow & 7) << 4);
  constexpr float LOG2E = 1.4426950408889634f;

  for (int kt = 0; kt <= qt; ++kt) {
    __syncthreads();
    // ---- stage K (global_load_lds, swizzled source) ----
#pragma unroll
    for (int q2 = 0; q2 < 2; q2++) {
      const int kvrow = kt * 64 + q2 * 32 + srow;
      const char* src =
          (const char*)(qkv + (size_t)(kvrow * 4 + n) * QKV_LD + E + h * 64) + kssw;
      gl_lds16(src, kl + q2 * 4096 + t * 16);
    }
    // ---- stage V transposed: Vt[d][kv] (reg path, conflict-free writes) ----
#pragma unroll
    for (int q2 = 0; q2 < 2; q2++) {
      const int r     = q2 * 32 + srow;
      const int kvrow = kt * 64 + r;
      const int c0    = scb >> 1;
      const bf16x8 vv = *(const bf16x8*)(qkv + (size_t)(kvrow * 4 + n) * QKV_LD +
                                         2 * E + h * 64 + c0);
#pragma unroll
      for (int i = 0; i < 8; i++) {
        const int d  = c0 + i;
        const int sw = ((d & 7) ^ (d >> 3)) << 4;
        *(__bf16*)(vt + d * 128 + ((2 * r) ^ sw)) = vv[i];
      }
    }
    __syncthreads();

    // ---- S = Q K^T over this 64-col KV tile ----
    f32x4 s[4];
#pragma unroll
    for (int ni = 0; ni < 4; ni++) s[ni] = f32x4{0.f, 0.f, 0.f, 0.f};
#pragma unroll
    for (int ni = 0; ni < 4; ni++) {
      const int row = ni * 16 + c;
      const int sw  = (row & 7) << 4;
#pragma unroll
      for (int ks = 0; ks < 2; ks++) {
        const bf16x8 kb = *(const bf16x8*)(kl + row * 128 + ((ks * 64 + g * 16) ^ sw));
        s[ni] = __builtin_amdgcn_mfma_f32_16x16x32_bf16(qa[ks], kb, s[ni], 0, 0, 0);
      }
    }

    // ---- online softmax (rows r live in lanes g*4+r across 16-lane groups) ----
    float p[4][4];
    float rmax[4];
    const bool lastTile = (kt == qt);
#pragma unroll
    for (int r = 0; r < 4; r++) rmax[r] = -3e38f;
#pragma unroll
    for (int ni = 0; ni < 4; ni++) {
      const int kvcol = kt * 64 + ni * 16 + c;
#pragma unroll
      for (int r = 0; r < 4; r++) {
        float v = s[ni][r] * 0.125f;
        if (lastTile) {
          const int qrow = qt * 64 + w * 16 + g * 4 + r;
          if (kvcol > qrow) v = -3e38f;
        }
        p[ni][r] = v;
        rmax[r]  = fmaxf(rmax[r], v);
      }
    }
#pragma unroll
    for (int r = 0; r < 4; r++) {
      float v = rmax[r];
      v = fmaxf(v, __shfl_xor(v, 1));
      v = fmaxf(v, __shfl_xor(v, 2));
      v = fmaxf(v, __shfl_xor(v, 4));
      v = fmaxf(v, __shfl_xor(v, 8));
      rmax[r] = v;
    }
    float alpha[4], rsum[4];
#pragma unroll
    for (int r = 0; r < 4; r++) {
      const float mnew = fmaxf(mrow[r], rmax[r]);
      alpha[r] = exp2f((mrow[r] - mnew) * LOG2E);
      mrow[r]  = mnew;
      rsum[r]  = 0.f;
    }
#pragma unroll
    for (int ni = 0; ni < 4; ni++)
#pragma unroll
      for (int r = 0; r < 4; r++) {
        const float e = exp2f((p[ni][r] - mrow[r]) * LOG2E);
        p[ni][r] = e;
        rsum[r] += e;
      }
#pragma unroll
    for (int r = 0; r < 4; r++) {
      float v = rsum[r];
      v += __shfl_xor(v, 1);
      v += __shfl_xor(v, 2);
      v += __shfl_xor(v, 4);
      v += __shfl_xor(v, 8);
      lrow[r] = lrow[r] * alpha[r] + v;
#pragma unroll
      for (int ni = 0; ni < 4; ni++) o[ni][r] *= alpha[r];
    }

    // ---- P (bf16) -> per-wave LDS, then read back as A-fragments ----
    char* pw = pl[w];
#pragma unroll
    for (int ni = 0; ni < 4; ni++)
#pragma unroll
      for (int r = 0; r < 4; r++) {
        const int prow = g * 4 + r;
        const int pb   = (2 * (ni * 16 + c)) ^ ((prow & 7) << 4);
        *(__bf16*)(pw + prow * 128 + pb) = (__bf16)p[ni][r];
      }
    bf16x8 pa[2];
    {
      const int sw = (c & 7) << 4;
      pa[0] = *(const bf16x8*)(pw + c * 128 + ((g * 16) ^ sw));
      pa[1] = *(const bf16x8*)(pw + c * 128 + ((64 + g * 16) ^ sw));
    }
    // ---- O += P V ----
#pragma unroll
    for (int ni = 0; ni < 4; ni++) {
      const int d  = ni * 16 + c;
      const int sw = ((d & 7) ^ (d >> 3)) << 4;
#pragma unroll
      for (int ks = 0; ks < 2; ks++) {
        const bf16x8 vb = *(const bf16x8*)(vt + d * 128 + ((ks * 64 + g * 16) ^ sw));
        o[ni] = __builtin_amdgcn_mfma_f32_16x16x32_bf16(pa[ks], vb, o[ni], 0, 0, 0);
      }
    }
  }

  // ---- epilogue: out[(qrow*4+n)*1024 + h*64 + d] = o / l ----
#pragma unroll
  for (int r = 0; r < 4; r++) {
    const float inv  = 1.f / lrow[r];
    const int   qrow = qt * 64 + w * 16 + g * 4 + r;
#pragma unroll
    for (int ni = 0; ni < 4; ni++) {
      const size_t off = (size_t)(qrow * 4 + n) * E + h * 64 + ni * 16 + c;
      out[off] = (__bf16)(o[ni][r] * inv);
    }
  }
}

// =====================================================================
extern "C" void kernel_launch(void* const* d_in, const int* in_sizes, int n_in,
                              void* d_out, int out_size, void* d_ws, size_t ws_size,
                              hipStream_t stream) {
  const float* x    = (const float*)d_in[0];   // [8192, 1024] fp32
  const float* wqkv = (const float*)d_in[1];   // [3072, 1024] fp32
  const float* wout = (const float*)d_in[2];   // [1024, 1024] fp32
  // d_in[3] = causal mask: fixed strict-upper-triangle, hardcoded in attn kernel.

  char* ws = (char*)d_ws;
  __bf16* x_bf    = (__bf16*)ws;                         ws += (size_t)M * E * 2;        // 16 MB
  __bf16* wqkv_bf = (__bf16*)ws;                         ws += (size_t)QKV_LD * E * 2;   //  6 MB
  __bf16* wout_bf = (__bf16*)ws;                         ws += (size_t)E * E * 2;        //  2 MB
  __bf16* qkv     = (__bf16*)ws;                         ws += (size_t)M * QKV_LD * 2;   // 48 MB
  __bf16* attno   = (__bf16*)ws;                                                         // 16 MB
  float*  outp    = (float*)d_out;

  cvt_f32_bf16<<<(M * E / 4) / 256, 256, 0, stream>>>(x, x_bf, M * E / 4);
  cvt_f32_bf16<<<(QKV_LD * E / 4) / 256, 256, 0, stream>>>(wqkv, wqkv_bf, QKV_LD * E / 4);
  cvt_f32_bf16<<<(E * E / 4) / 256, 256, 0, stream>>>(wout, wout_bf, E * E / 4);

  gemm_bt<QKV_LD, __bf16><<<dim3(QKV_LD / 128, M / 128), 256, 0, stream>>>(x_bf, wqkv_bf, qkv);
  attn_kernel<<<dim3(L / 64, NB * H), 256, 0, stream>>>(qkv, attno);
  gemm_bt<E, float><<<dim3(E / 128, M / 128), 256, 0, stream>>>(attno, wout_bf, outp);
}

// Round 4
// 258.393 us; speedup vs baseline: 1.4110x; 1.4110x over previous
//
#include <hip/hip_runtime.h>
#include <hip/hip_bf16.h>
#include <stdint.h>

// ---------------- problem geometry ----------------
constexpr int L  = 2048;
constexpr int NB = 4;                 // batch
constexpr int E  = 1024;
constexpr int H  = 16;
constexpr int M  = L * NB;            // 8192 tokens
constexpr int K  = E;                 // 1024 (GEMM inner dim)
constexpr int QKV_LD = 3 * E;         // 3072

typedef float  f32x4  __attribute__((ext_vector_type(4)));
typedef __bf16 bf16x4 __attribute__((ext_vector_type(4)));
typedef __bf16 bf16x8 __attribute__((ext_vector_type(8)));

#define AS1 __attribute__((address_space(1)))
#define AS3 __attribute__((address_space(3)))

static __device__ __forceinline__ void gl_lds16(const void* g, void* l) {
  __builtin_amdgcn_global_load_lds((const AS1 uint32_t*)g, (AS3 uint32_t*)l, 16, 0, 0);
}

// =====================================================================
// fp32 -> bf16 bulk convert
// =====================================================================
__global__ __launch_bounds__(256)
void cvt_f32_bf16(const float* __restrict__ in, __bf16* __restrict__ out, int n4) {
  const int i = blockIdx.x * blockDim.x + threadIdx.x;
  if (i < n4) {
    const f32x4 v = ((const f32x4*)in)[i];
    bf16x4 o;
#pragma unroll
    for (int j = 0; j < 4; j++) o[j] = (__bf16)v[j];
    ((bf16x4*)out)[i] = o;
  }
}

// =====================================================================
// GEMM: C[M][NC] = A[M][K] * B[NC][K]^T  (bf16 in, fp32 accum, OutT out)
// =====================================================================
template<int NC, typename OutT>
__global__ __launch_bounds__(256)
void gemm_bt(const __bf16* __restrict__ A, const __bf16* __restrict__ B,
             OutT* __restrict__ C) {
  constexpr int BK = 64;
  __shared__ char lds[2 * 128 * BK * 2];
  char* aL = lds;
  char* bL = lds + 128 * BK * 2;

  const int t    = threadIdx.x;
  const int lane = t & 63;
  const int w    = t >> 6;
  const int g    = lane >> 4;
  const int c    = lane & 15;

  const int rowBase = blockIdx.y * 128;
  const int colBase = blockIdx.x * 128;

  const int srow = t >> 3;
  const int scb  = (t & 7) * 16;
  const int ssw  = scb ^ ((srow & 7) << 4);

  const char* aSrcBase = (const char*)(A + (size_t)(rowBase + srow) * K) + ssw;
  const char* bSrcBase = (const char*)(B + (size_t)(colBase + srow) * K) + ssw;

  f32x4 acc[4][4];
#pragma unroll
  for (int i = 0; i < 4; i++)
#pragma unroll
    for (int j = 0; j < 4; j++) acc[i][j] = f32x4{0.f, 0.f, 0.f, 0.f};

  const int wr = (w >> 1) * 64;
  const int wc = (w & 1) * 64;

  for (int k0 = 0; k0 < K; k0 += BK) {
    __syncthreads();
#pragma unroll
    for (int q = 0; q < 4; q++) {
      gl_lds16(aSrcBase + (size_t)2 * k0 + (size_t)q * 32 * K * 2, aL + q * 4096 + t * 16);
      gl_lds16(bSrcBase + (size_t)2 * k0 + (size_t)q * 32 * K * 2, bL + q * 4096 + t * 16);
    }
    __syncthreads();

    bf16x8 af[4][2], bfR[4][2];
#pragma unroll
    for (int mi = 0; mi < 4; mi++) {
      const int row = wr + mi * 16 + c;
      const int sw  = (row & 7) << 4;
#pragma unroll
      for (int ks = 0; ks < 2; ks++)
        af[mi][ks] = *(const bf16x8*)(aL + row * 128 + ((ks * 64 + g * 16) ^ sw));
    }
#pragma unroll
    for (int ni = 0; ni < 4; ni++) {
      const int row = wc + ni * 16 + c;
      const int sw  = (row & 7) << 4;
#pragma unroll
      for (int ks = 0; ks < 2; ks++)
        bfR[ni][ks] = *(const bf16x8*)(bL + row * 128 + ((ks * 64 + g * 16) ^ sw));
    }
#pragma unroll
    for (int mi = 0; mi < 4; mi++)
#pragma unroll
      for (int ni = 0; ni < 4; ni++)
#pragma unroll
        for (int ks = 0; ks < 2; ks++)
          acc[mi][ni] = __builtin_amdgcn_mfma_f32_16x16x32_bf16(
              af[mi][ks], bfR[ni][ks], acc[mi][ni], 0, 0, 0);
  }

#pragma unroll
  for (int mi = 0; mi < 4; mi++)
#pragma unroll
    for (int ni = 0; ni < 4; ni++)
#pragma unroll
      for (int r = 0; r < 4; r++) {
        const int row = rowBase + wr + mi * 16 + g * 4 + r;
        const int col = colBase + wc + ni * 16 + c;
        C[(size_t)row * NC + col] = (OutT)acc[mi][ni][r];
      }
}

// =====================================================================
// Causal flash attention over qkv buffer [M][3072]
//   q at col h*64, k at 1024+h*64, v at 2048+h*64, token row = l*4+n
// Balanced: block (qx, b) handles q-tiles {qx, 31-qx} -> uniform 33 iters.
// grid (16, 64); block 256 = 4 waves; wave w owns q rows qt*64+w*16..+15.
// Attn body identical to the round-2 validated version (V scalar-transpose,
// P via per-wave swizzled LDS), plus setprio around MFMA clusters and the
// 1/8 scale folded into the Q fragments (exact: power of two).
// =====================================================================
__global__ __launch_bounds__(256)
void attn_kernel(const __bf16* __restrict__ qkv, __bf16* __restrict__ out) {
  const int qx = blockIdx.x;            // 0..15
  const int b  = blockIdx.y;
  const int n  = b >> 4;
  const int h  = b & 15;

  __shared__ char kl[64 * 128];       // K tile [kv][d], swizzled (row&7)<<4
  __shared__ char vt[64 * 128];       // V^T   [d][kv], swizzled ((d&7)^(d>>3))<<4
  __shared__ char pl[4][16 * 128];    // per-wave P [q16][kv64], swizzled (row&7)<<4

  const int t    = threadIdx.x;
  const int lane = t & 63;
  const int w    = t >> 6;
  const int g    = lane >> 4;
  const int c    = lane & 15;

  const int srow = t >> 3;            // 0..31
  const int scb  = (t & 7) * 16;
  const int kssw = scb ^ ((srow & 7) << 4);
  constexpr float LOG2E = 1.4426950408889634f;

  char* pw = pl[w];

  for (int pass = 0; pass < 2; ++pass) {
    const int qt = pass ? 31 - qx : qx;

    // Q fragments in registers, pre-scaled by dh^-0.5 = 0.125 (exact in bf16)
    bf16x8 qa0, qa1;
    {
      const int qrow = qt * 64 + w * 16 + c;
      const __bf16* qp = qkv + (size_t)(qrow * 4 + n) * QKV_LD + h * 64;
      qa0 = *(const bf16x8*)(qp + g * 8);
      qa1 = *(const bf16x8*)(qp + 32 + g * 8);
#pragma unroll
      for (int i = 0; i < 8; i++) {
        qa0[i] = (__bf16)((float)qa0[i] * 0.125f);
        qa1[i] = (__bf16)((float)qa1[i] * 0.125f);
      }
    }

    float mrow[4], lrow[4];
    f32x4 o[4];
#pragma unroll
    for (int r = 0; r < 4; r++) { mrow[r] = -3e38f; lrow[r] = 0.f; }
#pragma unroll
    for (int ni = 0; ni < 4; ni++) o[ni] = f32x4{0.f, 0.f, 0.f, 0.f};

    for (int kt = 0; kt <= qt; ++kt) {
      __syncthreads();
      // ---- stage K (global_load_lds, swizzled source) ----
#pragma unroll
      for (int q2 = 0; q2 < 2; q2++) {
        const int kvrow = kt * 64 + q2 * 32 + srow;
        const char* src =
            (const char*)(qkv + (size_t)(kvrow * 4 + n) * QKV_LD + E + h * 64) + kssw;
        gl_lds16(src, kl + q2 * 4096 + t * 16);
      }
      // ---- stage V transposed: Vt[d][kv] (reg path) ----
#pragma unroll
      for (int q2 = 0; q2 < 2; q2++) {
        const int r     = q2 * 32 + srow;
        const int kvrow = kt * 64 + r;
        const int c0    = scb >> 1;
        const bf16x8 vv = *(const bf16x8*)(qkv + (size_t)(kvrow * 4 + n) * QKV_LD +
                                           2 * E + h * 64 + c0);
#pragma unroll
        for (int i = 0; i < 8; i++) {
          const int d  = c0 + i;
          const int sw = ((d & 7) ^ (d >> 3)) << 4;
          *(__bf16*)(vt + d * 128 + ((2 * r) ^ sw)) = vv[i];
        }
      }
      __syncthreads();

      // ---- S = (Q/8) K^T over this 64-col KV tile ----
      f32x4 s[4];
#pragma unroll
      for (int ni = 0; ni < 4; ni++) s[ni] = f32x4{0.f, 0.f, 0.f, 0.f};
      __builtin_amdgcn_s_setprio(1);
#pragma unroll
      for (int ni = 0; ni < 4; ni++) {
        const int row = ni * 16 + c;
        const int sw  = (row & 7) << 4;
        const bf16x8 kb0 = *(const bf16x8*)(kl + row * 128 + ((g * 16) ^ sw));
        const bf16x8 kb1 = *(const bf16x8*)(kl + row * 128 + ((64 + g * 16) ^ sw));
        s[ni] = __builtin_amdgcn_mfma_f32_16x16x32_bf16(qa0, kb0, s[ni], 0, 0, 0);
        s[ni] = __builtin_amdgcn_mfma_f32_16x16x32_bf16(qa1, kb1, s[ni], 0, 0, 0);
      }
      __builtin_amdgcn_s_setprio(0);

      // ---- online softmax (rows r live in lanes g*4+r across 16-lane groups) ----
      float p[4][4], rmax[4];
      const bool lastTile = (kt == qt);
#pragma unroll
      for (int r = 0; r < 4; r++) rmax[r] = -3e38f;
#pragma unroll
      for (int ni = 0; ni < 4; ni++) {
        const int kvcol = kt * 64 + ni * 16 + c;
#pragma unroll
        for (int r = 0; r < 4; r++) {
          float v = s[ni][r];
          if (lastTile) {
            const int qrow = qt * 64 + w * 16 + g * 4 + r;
            if (kvcol > qrow) v = -3e38f;
          }
          p[ni][r] = v;
          rmax[r]  = fmaxf(rmax[r], v);
        }
      }
#pragma unroll
      for (int r = 0; r < 4; r++) {
        float v = rmax[r];
        v = fmaxf(v, __shfl_xor(v, 1));
        v = fmaxf(v, __shfl_xor(v, 2));
        v = fmaxf(v, __shfl_xor(v, 4));
        v = fmaxf(v, __shfl_xor(v, 8));
        rmax[r] = v;
      }
      float alpha[4], rsum[4];
#pragma unroll
      for (int r = 0; r < 4; r++) {
        const float mnew = fmaxf(mrow[r], rmax[r]);
        alpha[r] = exp2f((mrow[r] - mnew) * LOG2E);
        mrow[r]  = mnew;
        rsum[r]  = 0.f;
      }
#pragma unroll
      for (int ni = 0; ni < 4; ni++)
#pragma unroll
        for (int r = 0; r < 4; r++) {
          const float e = exp2f((p[ni][r] - mrow[r]) * LOG2E);
          p[ni][r] = e;
          rsum[r] += e;
        }
#pragma unroll
      for (int r = 0; r < 4; r++) {
        float v = rsum[r];
        v += __shfl_xor(v, 1);
        v += __shfl_xor(v, 2);
        v += __shfl_xor(v, 4);
        v += __shfl_xor(v, 8);
        lrow[r] = lrow[r] * alpha[r] + v;
#pragma unroll
        for (int ni = 0; ni < 4; ni++) o[ni][r] *= alpha[r];
      }

      // ---- P (bf16) -> per-wave LDS, then read back as A-fragments ----
#pragma unroll
      for (int ni = 0; ni < 4; ni++)
#pragma unroll
        for (int r = 0; r < 4; r++) {
          const int prow = g * 4 + r;
          const int pb   = (2 * (ni * 16 + c)) ^ ((prow & 7) << 4);
          *(__bf16*)(pw + prow * 128 + pb) = (__bf16)p[ni][r];
        }
      bf16x8 pa[2];
      {
        const int sw = (c & 7) << 4;
        pa[0] = *(const bf16x8*)(pw + c * 128 + ((g * 16) ^ sw));
        pa[1] = *(const bf16x8*)(pw + c * 128 + ((64 + g * 16) ^ sw));
      }
      // ---- O += P V ----
      __builtin_amdgcn_s_setprio(1);
#pragma unroll
      for (int ni = 0; ni < 4; ni++) {
        const int d  = ni * 16 + c;
        const int sw = ((d & 7) ^ (d >> 3)) << 4;
#pragma unroll
        for (int ks = 0; ks < 2; ks++) {
          const bf16x8 vb = *(const bf16x8*)(vt + d * 128 + ((ks * 64 + g * 16) ^ sw));
          o[ni] = __builtin_amdgcn_mfma_f32_16x16x32_bf16(pa[ks], vb, o[ni], 0, 0, 0);
        }
      }
      __builtin_amdgcn_s_setprio(0);
    }

    // ---- epilogue ----
#pragma unroll
    for (int r = 0; r < 4; r++) {
      const float inv  = 1.f / lrow[r];
      const int   qrow = qt * 64 + w * 16 + g * 4 + r;
#pragma unroll
      for (int ni = 0; ni < 4; ni++) {
        const size_t off = (size_t)(qrow * 4 + n) * E + h * 64 + ni * 16 + c;
        out[off] = (__bf16)(o[ni][r] * inv);
      }
    }
  }
}

// =====================================================================
extern "C" void kernel_launch(void* const* d_in, const int* in_sizes, int n_in,
                              void* d_out, int out_size, void* d_ws, size_t ws_size,
                              hipStream_t stream) {
  const float* x    = (const float*)d_in[0];
  const float* wqkv = (const float*)d_in[1];
  const float* wout = (const float*)d_in[2];

  char* ws = (char*)d_ws;
  __bf16* x_bf    = (__bf16*)ws;                         ws += (size_t)M * E * 2;
  __bf16* wqkv_bf = (__bf16*)ws;                         ws += (size_t)QKV_LD * E * 2;
  __bf16* wout_bf = (__bf16*)ws;                         ws += (size_t)E * E * 2;
  __bf16* qkv     = (__bf16*)ws;                         ws += (size_t)M * QKV_LD * 2;
  __bf16* attno   = (__bf16*)ws;
  float*  outp    = (float*)d_out;

  cvt_f32_bf16<<<(M * E / 4) / 256, 256, 0, stream>>>(x, x_bf, M * E / 4);
  cvt_f32_bf16<<<(QKV_LD * E / 4) / 256, 256, 0, stream>>>(wqkv, wqkv_bf, QKV_LD * E / 4);
  cvt_f32_bf16<<<(E * E / 4) / 256, 256, 0, stream>>>(wout, wout_bf, E * E / 4);

  gemm_bt<QKV_LD, __bf16><<<dim3(QKV_LD / 128, M / 128), 256, 0, stream>>>(x_bf, wqkv_bf, qkv);
  attn_kernel<<<dim3(16, NB * H), 256, 0, stream>>>(qkv, attno);
  gemm_bt<E, float><<<dim3(E / 128, M / 128), 256, 0, stream>>>(attno, wout_bf, outp);
}

// Round 5
// 251.046 us; speedup vs baseline: 1.4523x; 1.0293x over previous
//
#include <hip/hip_runtime.h>
#include <hip/hip_bf16.h>
#include <stdint.h>

// ---------------- problem geometry ----------------
constexpr int L  = 2048;
constexpr int NB = 4;                 // batch
constexpr int E  = 1024;
constexpr int H  = 16;
constexpr int M  = L * NB;            // 8192 tokens
constexpr int K  = E;                 // 1024 (GEMM inner dim)
constexpr int QKV_LD = 3 * E;         // 3072

typedef float  f32x4  __attribute__((ext_vector_type(4)));
typedef __bf16 bf16x4 __attribute__((ext_vector_type(4)));
typedef __bf16 bf16x8 __attribute__((ext_vector_type(8)));

#define AS1 __attribute__((address_space(1)))
#define AS3 __attribute__((address_space(3)))

static __device__ __forceinline__ void gl_lds16(const void* g, void* l) {
  __builtin_amdgcn_global_load_lds((const AS1 uint32_t*)g, (AS3 uint32_t*)l, 16, 0, 0);
}

// =====================================================================
// fp32 -> bf16 bulk convert
// =====================================================================
__global__ __launch_bounds__(256)
void cvt_f32_bf16(const float* __restrict__ in, __bf16* __restrict__ out, int n4) {
  const int i = blockIdx.x * blockDim.x + threadIdx.x;
  if (i < n4) {
    const f32x4 v = ((const f32x4*)in)[i];
    bf16x4 o;
#pragma unroll
    for (int j = 0; j < 4; j++) o[j] = (__bf16)v[j];
    ((bf16x4*)out)[i] = o;
  }
}

// =====================================================================
// GEMM: C[M][NC] = A[M][K] * B[NC][K]^T  (bf16 in, fp32 accum, OutT out)
// =====================================================================
template<int NC, typename OutT>
__global__ __launch_bounds__(256)
void gemm_bt(const __bf16* __restrict__ A, const __bf16* __restrict__ B,
             OutT* __restrict__ C) {
  constexpr int BK = 64;
  __shared__ char lds[2 * 128 * BK * 2];
  char* aL = lds;
  char* bL = lds + 128 * BK * 2;

  const int t    = threadIdx.x;
  const int lane = t & 63;
  const int w    = t >> 6;
  const int g    = lane >> 4;
  const int c    = lane & 15;

  const int rowBase = blockIdx.y * 128;
  const int colBase = blockIdx.x * 128;

  const int srow = t >> 3;
  const int scb  = (t & 7) * 16;
  const int ssw  = scb ^ ((srow & 7) << 4);

  const char* aSrcBase = (const char*)(A + (size_t)(rowBase + srow) * K) + ssw;
  const char* bSrcBase = (const char*)(B + (size_t)(colBase + srow) * K) + ssw;

  f32x4 acc[4][4];
#pragma unroll
  for (int i = 0; i < 4; i++)
#pragma unroll
    for (int j = 0; j < 4; j++) acc[i][j] = f32x4{0.f, 0.f, 0.f, 0.f};

  const int wr = (w >> 1) * 64;
  const int wc = (w & 1) * 64;

  for (int k0 = 0; k0 < K; k0 += BK) {
    __syncthreads();
#pragma unroll
    for (int q = 0; q < 4; q++) {
      gl_lds16(aSrcBase + (size_t)2 * k0 + (size_t)q * 32 * K * 2, aL + q * 4096 + t * 16);
      gl_lds16(bSrcBase + (size_t)2 * k0 + (size_t)q * 32 * K * 2, bL + q * 4096 + t * 16);
    }
    __syncthreads();

    bf16x8 af[4][2], bfR[4][2];
#pragma unroll
    for (int mi = 0; mi < 4; mi++) {
      const int row = wr + mi * 16 + c;
      const int sw  = (row & 7) << 4;
#pragma unroll
      for (int ks = 0; ks < 2; ks++)
        af[mi][ks] = *(const bf16x8*)(aL + row * 128 + ((ks * 64 + g * 16) ^ sw));
    }
#pragma unroll
    for (int ni = 0; ni < 4; ni++) {
      const int row = wc + ni * 16 + c;
      const int sw  = (row & 7) << 4;
#pragma unroll
      for (int ks = 0; ks < 2; ks++)
        bfR[ni][ks] = *(const bf16x8*)(bL + row * 128 + ((ks * 64 + g * 16) ^ sw));
    }
#pragma unroll
    for (int mi = 0; mi < 4; mi++)
#pragma unroll
      for (int ni = 0; ni < 4; ni++)
#pragma unroll
        for (int ks = 0; ks < 2; ks++)
          acc[mi][ni] = __builtin_amdgcn_mfma_f32_16x16x32_bf16(
              af[mi][ks], bfR[ni][ks], acc[mi][ni], 0, 0, 0);
  }

#pragma unroll
  for (int mi = 0; mi < 4; mi++)
#pragma unroll
    for (int ni = 0; ni < 4; ni++)
#pragma unroll
      for (int r = 0; r < 4; r++) {
        const int row = rowBase + wr + mi * 16 + g * 4 + r;
        const int col = colBase + wc + ni * 16 + c;
        C[(size_t)row * NC + col] = (OutT)acc[mi][ni][r];
      }
}

// =====================================================================
// V transpose: qkv V-section [l][n][h*64+d] -> vT[(n*16+h)*64+d][l]
// LDS-tiled 64x64, XOR-swizzled; coalesced on both global sides.
// =====================================================================
__global__ __launch_bounds__(256)
void transpose_v(const __bf16* __restrict__ qkv, __bf16* __restrict__ vT) {
  __shared__ char tile[64 * 160];     // elem(l,d) at l*160 + ((d*2) ^ (((l>>3)&7)<<4))
  const int lt = blockIdx.x;          // l-tile 0..31
  const int bh = blockIdx.y;          // n*16+h
  const int n  = bh >> 4, h = bh & 15;
  const int t  = threadIdx.x;
  const int r8 = t >> 3;              // 0..31
  const int c8 = (t & 7) * 8;         // 0..56

#pragma unroll
  for (int q2 = 0; q2 < 2; q2++) {
    const int l = q2 * 32 + r8;
    const bf16x8 v = *(const bf16x8*)(qkv + (size_t)((lt * 64 + l) * 4 + n) * QKV_LD +
                                      2 * E + h * 64 + c8);
    *(bf16x8*)(tile + l * 160 + ((c8 * 2) ^ (((l >> 3) & 7) << 4))) = v;
  }
  __syncthreads();
#pragma unroll
  for (int q2 = 0; q2 < 2; q2++) {
    const int d = q2 * 32 + r8;
    bf16x8 o;
#pragma unroll
    for (int i = 0; i < 8; i++) {
      const int l = c8 + i;
      o[i] = *(const __bf16*)(tile + l * 160 + ((d * 2) ^ (((l >> 3) & 7) << 4)));
    }
    *(bf16x8*)(vT + ((size_t)bh * 64 + d) * 2048 + lt * 64 + c8) = o;
  }
}

// =====================================================================
// Causal flash attention. Balanced: block (qx,b) does q-tiles {qx,31-qx}.
// K and V^T both staged via global_load_lds with the same row-swizzle;
// QK^T and PV fragment reads are mirrors of each other (ds_read_b128).
// log2(e)/8 folded into the Q prescale -> exp2 with no multiply.
// =====================================================================
__global__ __launch_bounds__(256)
void attn_kernel(const __bf16* __restrict__ qkv, const __bf16* __restrict__ vT,
                 __bf16* __restrict__ out) {
  const int qx = blockIdx.x;            // 0..15
  const int b  = blockIdx.y;
  const int n  = b >> 4;
  const int h  = b & 15;

  __shared__ char kl[64 * 128];       // K tile [kv][d], swizzled (row&7)<<4
  __shared__ char vl[64 * 128];       // V^T tile [d][kv], swizzled (row&7)<<4
  __shared__ char pl[4][16 * 128];    // per-wave P [q16][kv64], swizzled (row&7)<<4

  const int t    = threadIdx.x;
  const int lane = t & 63;
  const int w    = t >> 6;
  const int g    = lane >> 4;
  const int c    = lane & 15;

  const int srow = t >> 3;            // 0..31
  const int scb  = (t & 7) * 16;
  const int kssw = scb ^ ((srow & 7) << 4);

  // scale = dh^-0.5 * log2(e): S is computed in log2-units -> exp2 direct
  constexpr float QSCALE = 0.125f * 1.4426950408889634f;

  char* pw = pl[w];

  for (int pass = 0; pass < 2; ++pass) {
    const int qt = pass ? 31 - qx : qx;

    bf16x8 qa0, qa1;
    {
      const int qrow = qt * 64 + w * 16 + c;
      const __bf16* qp = qkv + (size_t)(qrow * 4 + n) * QKV_LD + h * 64;
      qa0 = *(const bf16x8*)(qp + g * 8);
      qa1 = *(const bf16x8*)(qp + 32 + g * 8);
#pragma unroll
      for (int i = 0; i < 8; i++) {
        qa0[i] = (__bf16)((float)qa0[i] * QSCALE);
        qa1[i] = (__bf16)((float)qa1[i] * QSCALE);
      }
    }

    float mrow[4], lrow[4];
    f32x4 o[4];
#pragma unroll
    for (int r = 0; r < 4; r++) { mrow[r] = -3e38f; lrow[r] = 0.f; }
#pragma unroll
    for (int ni = 0; ni < 4; ni++) o[ni] = f32x4{0.f, 0.f, 0.f, 0.f};

    for (int kt = 0; kt <= qt; ++kt) {
      __syncthreads();
      // ---- stage K rows + V^T rows (global_load_lds, swizzled source) ----
#pragma unroll
      for (int q2 = 0; q2 < 2; q2++) {
        const int kvrow = kt * 64 + q2 * 32 + srow;
        gl_lds16((const char*)(qkv + (size_t)(kvrow * 4 + n) * QKV_LD + E + h * 64) + kssw,
                 kl + q2 * 4096 + t * 16);
        const int vd = q2 * 32 + srow;
        gl_lds16((const char*)(vT + ((size_t)b * 64 + vd) * 2048 + kt * 64) + kssw,
                 vl + q2 * 4096 + t * 16);
      }
      __syncthreads();

      // ---- S' = (Q*qscale) K^T  (log2-units) ----
      f32x4 s[4];
#pragma unroll
      for (int ni = 0; ni < 4; ni++) s[ni] = f32x4{0.f, 0.f, 0.f, 0.f};
      __builtin_amdgcn_s_setprio(1);
#pragma unroll
      for (int ni = 0; ni < 4; ni++) {
        const int row = ni * 16 + c;
        const int sw  = (row & 7) << 4;
        const bf16x8 kb0 = *(const bf16x8*)(kl + row * 128 + ((g * 16) ^ sw));
        const bf16x8 kb1 = *(const bf16x8*)(kl + row * 128 + ((64 + g * 16) ^ sw));
        s[ni] = __builtin_amdgcn_mfma_f32_16x16x32_bf16(qa0, kb0, s[ni], 0, 0, 0);
        s[ni] = __builtin_amdgcn_mfma_f32_16x16x32_bf16(qa1, kb1, s[ni], 0, 0, 0);
      }
      __builtin_amdgcn_s_setprio(0);

      // ---- online softmax (rows r live in lanes g*4+r across 16-lane groups) ----
      float p[4][4], rmax[4];
      const bool lastTile = (kt == qt);
#pragma unroll
      for (int r = 0; r < 4; r++) rmax[r] = -3e38f;
#pragma unroll
      for (int ni = 0; ni < 4; ni++) {
        const int kvcol = kt * 64 + ni * 16 + c;
#pragma unroll
        for (int r = 0; r < 4; r++) {
          float v = s[ni][r];
          if (lastTile) {
            const int qrow = qt * 64 + w * 16 + g * 4 + r;
            if (kvcol > qrow) v = -3e38f;
          }
          p[ni][r] = v;
          rmax[r]  = fmaxf(rmax[r], v);
        }
      }
#pragma unroll
      for (int r = 0; r < 4; r++) {
        float v = rmax[r];
        v = fmaxf(v, __shfl_xor(v, 1));
        v = fmaxf(v, __shfl_xor(v, 2));
        v = fmaxf(v, __shfl_xor(v, 4));
        v = fmaxf(v, __shfl_xor(v, 8));
        rmax[r] = v;
      }
      float alpha[4], rsum[4];
#pragma unroll
      for (int r = 0; r < 4; r++) {
        const float mnew = fmaxf(mrow[r], rmax[r]);
        alpha[r] = exp2f(mrow[r] - mnew);
        mrow[r]  = mnew;
        rsum[r]  = 0.f;
      }
#pragma unroll
      for (int ni = 0; ni < 4; ni++)
#pragma unroll
        for (int r = 0; r < 4; r++) {
          const float e = exp2f(p[ni][r] - mrow[r]);
          p[ni][r] = e;
          rsum[r] += e;
        }
#pragma unroll
      for (int r = 0; r < 4; r++) {
        float v = rsum[r];
        v += __shfl_xor(v, 1);
        v += __shfl_xor(v, 2);
        v += __shfl_xor(v, 4);
        v += __shfl_xor(v, 8);
        lrow[r] = lrow[r] * alpha[r] + v;
#pragma unroll
        for (int ni = 0; ni < 4; ni++) o[ni][r] *= alpha[r];
      }

      // ---- P (bf16) -> per-wave LDS, then read back as A-fragments ----
#pragma unroll
      for (int ni = 0; ni < 4; ni++)
#pragma unroll
        for (int r = 0; r < 4; r++) {
          const int prow = g * 4 + r;
          const int pb   = (2 * (ni * 16 + c)) ^ ((prow & 7) << 4);
          *(__bf16*)(pw + prow * 128 + pb) = (__bf16)p[ni][r];
        }
      bf16x8 pa[2];
      {
        const int sw = (c & 7) << 4;
        pa[0] = *(const bf16x8*)(pw + c * 128 + ((g * 16) ^ sw));
        pa[1] = *(const bf16x8*)(pw + c * 128 + ((64 + g * 16) ^ sw));
      }
      // ---- O += P V  (B-fragments from vl, mirror of QK^T) ----
      __builtin_amdgcn_s_setprio(1);
#pragma unroll
      for (int ni = 0; ni < 4; ni++) {
        const int row = ni * 16 + c;
        const int sw  = (row & 7) << 4;
        const bf16x8 vb0 = *(const bf16x8*)(vl + row * 128 + ((g * 16) ^ sw));
        const bf16x8 vb1 = *(const bf16x8*)(vl + row * 128 + ((64 + g * 16) ^ sw));
        o[ni] = __builtin_amdgcn_mfma_f32_16x16x32_bf16(pa[0], vb0, o[ni], 0, 0, 0);
        o[ni] = __builtin_amdgcn_mfma_f32_16x16x32_bf16(pa[1], vb1, o[ni], 0, 0, 0);
      }
      __builtin_amdgcn_s_setprio(0);
    }

    // ---- epilogue ----
#pragma unroll
    for (int r = 0; r < 4; r++) {
      const float inv  = 1.f / lrow[r];
      const int   qrow = qt * 64 + w * 16 + g * 4 + r;
#pragma unroll
      for (int ni = 0; ni < 4; ni++) {
        const size_t off = (size_t)(qrow * 4 + n) * E + h * 64 + ni * 16 + c;
        out[off] = (__bf16)(o[ni][r] * inv);
      }
    }
  }
}

// =====================================================================
extern "C" void kernel_launch(void* const* d_in, const int* in_sizes, int n_in,
                              void* d_out, int out_size, void* d_ws, size_t ws_size,
                              hipStream_t stream) {
  const float* x    = (const float*)d_in[0];
  const float* wqkv = (const float*)d_in[1];
  const float* wout = (const float*)d_in[2];

  char* ws = (char*)d_ws;
  __bf16* x_bf    = (__bf16*)ws;                         ws += (size_t)M * E * 2;       // 16 MB
  __bf16* wqkv_bf = (__bf16*)ws;                         ws += (size_t)QKV_LD * E * 2;  //  6 MB
  __bf16* wout_bf = (__bf16*)ws;                         ws += (size_t)E * E * 2;       //  2 MB
  __bf16* qkv     = (__bf16*)ws;                         ws += (size_t)M * QKV_LD * 2;  // 48 MB
  __bf16* attno   = (__bf16*)ws;                                                        // 16 MB
  __bf16* vT      = x_bf;   // x_bf is dead after the QKV GEMM; reuse as vT (16 MB)
  float*  outp    = (float*)d_out;

  cvt_f32_bf16<<<(M * E / 4) / 256, 256, 0, stream>>>(x, x_bf, M * E / 4);
  cvt_f32_bf16<<<(QKV_LD * E / 4) / 256, 256, 0, stream>>>(wqkv, wqkv_bf, QKV_LD * E / 4);
  cvt_f32_bf16<<<(E * E / 4) / 256, 256, 0, stream>>>(wout, wout_bf, E * E / 4);

  gemm_bt<QKV_LD, __bf16><<<dim3(QKV_LD / 128, M / 128), 256, 0, stream>>>(x_bf, wqkv_bf, qkv);
  transpose_v<<<dim3(L / 64, NB * H), 256, 0, stream>>>(qkv, vT);
  attn_kernel<<<dim3(16, NB * H), 256, 0, stream>>>(qkv, vT, attno);
  gemm_bt<E, float><<<dim3(E / 128, M / 128), 256, 0, stream>>>(attno, wout_bf, outp);
}

// Round 6
// 204.430 us; speedup vs baseline: 1.7835x; 1.2280x over previous
//
#include <hip/hip_runtime.h>
#include <hip/hip_bf16.h>
#include <stdint.h>

// ---------------- problem geometry ----------------
constexpr int L  = 2048;
constexpr int NB = 4;                 // batch
constexpr int E  = 1024;
constexpr int H  = 16;
constexpr int M  = L * NB;            // 8192 tokens
constexpr int K  = E;                 // 1024 (GEMM inner dim)
constexpr int QKV_LD = 3 * E;         // 3072

typedef float  f32x4  __attribute__((ext_vector_type(4)));
typedef __bf16 bf16x4 __attribute__((ext_vector_type(4)));
typedef __bf16 bf16x8 __attribute__((ext_vector_type(8)));

#define AS1 __attribute__((address_space(1)))
#define AS3 __attribute__((address_space(3)))

static __device__ __forceinline__ void gl_lds16(const void* g, void* l) {
  __builtin_amdgcn_global_load_lds((const AS1 uint32_t*)g, (AS3 uint32_t*)l, 16, 0, 0);
}

// =====================================================================
// fp32 -> bf16 bulk convert
// =====================================================================
__global__ __launch_bounds__(256)
void cvt_f32_bf16(const float* __restrict__ in, __bf16* __restrict__ out, int n4) {
  const int i = blockIdx.x * blockDim.x + threadIdx.x;
  if (i < n4) {
    const f32x4 v = ((const f32x4*)in)[i];
    bf16x4 o;
#pragma unroll
    for (int j = 0; j < 4; j++) o[j] = (__bf16)v[j];
    ((bf16x4*)out)[i] = o;
  }
}

// =====================================================================
// GEMM: C[M][NC] = A[M][K] * B[NC][K]^T  (bf16 in, fp32 accum, OutT out)
// =====================================================================
template<int NC, typename OutT>
__global__ __launch_bounds__(256)
void gemm_bt(const __bf16* __restrict__ A, const __bf16* __restrict__ B,
             OutT* __restrict__ C) {
  constexpr int BK = 64;
  __shared__ char lds[2 * 128 * BK * 2];
  char* aL = lds;
  char* bL = lds + 128 * BK * 2;

  const int t    = threadIdx.x;
  const int lane = t & 63;
  const int w    = t >> 6;
  const int g    = lane >> 4;
  const int c    = lane & 15;

  const int rowBase = blockIdx.y * 128;
  const int colBase = blockIdx.x * 128;

  const int srow = t >> 3;
  const int scb  = (t & 7) * 16;
  const int ssw  = scb ^ ((srow & 7) << 4);

  const char* aSrcBase = (const char*)(A + (size_t)(rowBase + srow) * K) + ssw;
  const char* bSrcBase = (const char*)(B + (size_t)(colBase + srow) * K) + ssw;

  f32x4 acc[4][4];
#pragma unroll
  for (int i = 0; i < 4; i++)
#pragma unroll
    for (int j = 0; j < 4; j++) acc[i][j] = f32x4{0.f, 0.f, 0.f, 0.f};

  const int wr = (w >> 1) * 64;
  const int wc = (w & 1) * 64;

  for (int k0 = 0; k0 < K; k0 += BK) {
    __syncthreads();
#pragma unroll
    for (int q = 0; q < 4; q++) {
      gl_lds16(aSrcBase + (size_t)2 * k0 + (size_t)q * 32 * K * 2, aL + q * 4096 + t * 16);
      gl_lds16(bSrcBase + (size_t)2 * k0 + (size_t)q * 32 * K * 2, bL + q * 4096 + t * 16);
    }
    __syncthreads();

    bf16x8 af[4][2], bfR[4][2];
#pragma unroll
    for (int mi = 0; mi < 4; mi++) {
      const int row = wr + mi * 16 + c;
      const int sw  = (row & 7) << 4;
#pragma unroll
      for (int ks = 0; ks < 2; ks++)
        af[mi][ks] = *(const bf16x8*)(aL + row * 128 + ((ks * 64 + g * 16) ^ sw));
    }
#pragma unroll
    for (int ni = 0; ni < 4; ni++) {
      const int row = wc + ni * 16 + c;
      const int sw  = (row & 7) << 4;
#pragma unroll
      for (int ks = 0; ks < 2; ks++)
        bfR[ni][ks] = *(const bf16x8*)(bL + row * 128 + ((ks * 64 + g * 16) ^ sw));
    }
#pragma unroll
    for (int mi = 0; mi < 4; mi++)
#pragma unroll
      for (int ni = 0; ni < 4; ni++)
#pragma unroll
        for (int ks = 0; ks < 2; ks++)
          acc[mi][ni] = __builtin_amdgcn_mfma_f32_16x16x32_bf16(
              af[mi][ks], bfR[ni][ks], acc[mi][ni], 0, 0, 0);
  }

#pragma unroll
  for (int mi = 0; mi < 4; mi++)
#pragma unroll
    for (int ni = 0; ni < 4; ni++)
#pragma unroll
      for (int r = 0; r < 4; r++) {
        const int row = rowBase + wr + mi * 16 + g * 4 + r;
        const int col = colBase + wc + ni * 16 + c;
        C[(size_t)row * NC + col] = (OutT)acc[mi][ni][r];
      }
}

// =====================================================================
// V transpose: qkv V-section [l][n][h*64+d] -> vT[(n*16+h)*64+d][l]
// =====================================================================
__global__ __launch_bounds__(256)
void transpose_v(const __bf16* __restrict__ qkv, __bf16* __restrict__ vT) {
  __shared__ char tile[64 * 160];     // elem(l,d) at l*160 + ((d*2) ^ (((l>>3)&7)<<4))
  const int lt = blockIdx.x;          // l-tile 0..31
  const int bh = blockIdx.y;          // n*16+h
  const int n  = bh >> 4, h = bh & 15;
  const int t  = threadIdx.x;
  const int r8 = t >> 3;              // 0..31
  const int c8 = (t & 7) * 8;         // 0..56

#pragma unroll
  for (int q2 = 0; q2 < 2; q2++) {
    const int l = q2 * 32 + r8;
    const bf16x8 v = *(const bf16x8*)(qkv + (size_t)((lt * 64 + l) * 4 + n) * QKV_LD +
                                      2 * E + h * 64 + c8);
    *(bf16x8*)(tile + l * 160 + ((c8 * 2) ^ (((l >> 3) & 7) << 4))) = v;
  }
  __syncthreads();
#pragma unroll
  for (int q2 = 0; q2 < 2; q2++) {
    const int d = q2 * 32 + r8;
    bf16x8 o;
#pragma unroll
    for (int i = 0; i < 8; i++) {
      const int l = c8 + i;
      o[i] = *(const __bf16*)(tile + l * 160 + ((d * 2) ^ (((l >> 3) & 7) << 4)));
    }
    *(bf16x8*)(vT + ((size_t)bh * 64 + d) * 2048 + lt * 64 + c8) = o;
  }
}

// =====================================================================
// Causal flash attention. Balanced: block (qx,b) does q-tiles {qx,31-qx}.
// SWAPPED QK^T: s[ni] = mfma(K_frag, Q_frag) -> S^T; lane (c,g) holds
// q = w*16+c, kv = ni*16+g*4+r. Softmax state (m,l) is scalar per lane;
// row reductions are 2 shuffles (xor16/xor32). P packed to LDS with 4x
// ds_write_b64; P readback and PV identical to the validated path.
// =====================================================================
__global__ __launch_bounds__(256)
void attn_kernel(const __bf16* __restrict__ qkv, const __bf16* __restrict__ vT,
                 __bf16* __restrict__ out) {
  const int qx = blockIdx.x;            // 0..15
  const int b  = blockIdx.y;
  const int n  = b >> 4;
  const int h  = b & 15;

  __shared__ char kl[64 * 128];       // K tile [kv][d], swizzled (row&7)<<4
  __shared__ char vl[64 * 128];       // V^T tile [d][kv], swizzled (row&7)<<4
  __shared__ char pl[4][16 * 128];    // per-wave P [q16][kv64], swizzled (row&7)<<4

  const int t    = threadIdx.x;
  const int lane = t & 63;
  const int w    = t >> 6;
  const int g    = lane >> 4;
  const int c    = lane & 15;

  const int srow = t >> 3;            // 0..31
  const int scb  = (t & 7) * 16;
  const int kssw = scb ^ ((srow & 7) << 4);

  // scale = dh^-0.5 * log2(e): S in log2-units -> exp2 direct
  constexpr float QSCALE = 0.125f * 1.4426950408889634f;

  char* pw = pl[w];
  const int qloc = w * 16 + c;        // this lane's q row within the 64-tile

  for (int pass = 0; pass < 2; ++pass) {
    const int qt = pass ? 31 - qx : qx;

    bf16x8 qa0, qa1;
    {
      const int qrow = qt * 64 + qloc;
      const __bf16* qp = qkv + (size_t)(qrow * 4 + n) * QKV_LD + h * 64;
      qa0 = *(const bf16x8*)(qp + g * 8);
      qa1 = *(const bf16x8*)(qp + 32 + g * 8);
#pragma unroll
      for (int i = 0; i < 8; i++) {
        qa0[i] = (__bf16)((float)qa0[i] * QSCALE);
        qa1[i] = (__bf16)((float)qa1[i] * QSCALE);
      }
    }

    float m_c = -3e38f, l_c = 0.f;    // per-lane softmax state for q = qloc
    f32x4 o[4];
#pragma unroll
    for (int ni = 0; ni < 4; ni++) o[ni] = f32x4{0.f, 0.f, 0.f, 0.f};

    for (int kt = 0; kt <= qt; ++kt) {
      __syncthreads();
      // ---- stage K rows + V^T rows (global_load_lds, swizzled source) ----
#pragma unroll
      for (int q2 = 0; q2 < 2; q2++) {
        const int kvrow = kt * 64 + q2 * 32 + srow;
        gl_lds16((const char*)(qkv + (size_t)(kvrow * 4 + n) * QKV_LD + E + h * 64) + kssw,
                 kl + q2 * 4096 + t * 16);
        const int vd = q2 * 32 + srow;
        gl_lds16((const char*)(vT + ((size_t)b * 64 + vd) * 2048 + kt * 64) + kssw,
                 vl + q2 * 4096 + t * 16);
      }
      __syncthreads();

      // ---- S^T = K (Q*qscale)^T : s[ni] rows kv=ni*16+g*4+r, col q=c ----
      f32x4 s[4];
#pragma unroll
      for (int ni = 0; ni < 4; ni++) s[ni] = f32x4{0.f, 0.f, 0.f, 0.f};
      __builtin_amdgcn_s_setprio(1);
#pragma unroll
      for (int ni = 0; ni < 4; ni++) {
        const int row = ni * 16 + c;
        const int sw  = (row & 7) << 4;
        const bf16x8 kb0 = *(const bf16x8*)(kl + row * 128 + ((g * 16) ^ sw));
        const bf16x8 kb1 = *(const bf16x8*)(kl + row * 128 + ((64 + g * 16) ^ sw));
        s[ni] = __builtin_amdgcn_mfma_f32_16x16x32_bf16(kb0, qa0, s[ni], 0, 0, 0);
        s[ni] = __builtin_amdgcn_mfma_f32_16x16x32_bf16(kb1, qa1, s[ni], 0, 0, 0);
      }
      __builtin_amdgcn_s_setprio(0);

      // ---- online softmax, lane-local row (q=qloc), kv across regs+g ----
      const bool lastTile = (kt == qt);
      float rmax = -3e38f;
#pragma unroll
      for (int ni = 0; ni < 4; ni++)
#pragma unroll
        for (int r = 0; r < 4; r++) {
          float v = s[ni][r];
          if (lastTile && (ni * 16 + g * 4 + r > qloc)) v = -3e38f;
          s[ni][r] = v;
          rmax = fmaxf(rmax, v);
        }
      rmax = fmaxf(rmax, __shfl_xor(rmax, 16));
      rmax = fmaxf(rmax, __shfl_xor(rmax, 32));

      const float mnew  = fmaxf(m_c, rmax);
      const float alpha = exp2f(m_c - mnew);
      const bool  grow  = rmax > m_c;
      m_c = mnew;

      float rsum = 0.f;
#pragma unroll
      for (int ni = 0; ni < 4; ni++)
#pragma unroll
        for (int r = 0; r < 4; r++) {
          const float e = exp2f(s[ni][r] - mnew);
          s[ni][r] = e;
          rsum += e;
        }
      rsum += __shfl_xor(rsum, 16);
      rsum += __shfl_xor(rsum, 32);
      l_c = l_c * alpha + rsum;

      // O-rescale only when the running max actually grew (exact: alpha==1)
      if (__any(grow)) {
#pragma unroll
        for (int r = 0; r < 4; r++) {
          const float ar = __shfl(alpha, g * 4 + r);
#pragma unroll
          for (int ni = 0; ni < 4; ni++) o[ni][r] *= ar;
        }
      }

      // ---- P -> per-wave LDS: 4x packed ds_write_b64 (row q=c) ----
      // elem (q=c, kv=ni*16+g*4+r) at byte ((ni*32+g*8)+r*2) ^ ((c&7)<<4)
#pragma unroll
      for (int ni = 0; ni < 4; ni++) {
        bf16x4 pk;
#pragma unroll
        for (int r = 0; r < 4; r++) pk[r] = (__bf16)s[ni][r];
        *(bf16x4*)(pw + c * 128 + ((ni * 32 + g * 8) ^ ((c & 7) << 4))) = pk;
      }
      bf16x8 pa[2];
      {
        const int sw = (c & 7) << 4;
        pa[0] = *(const bf16x8*)(pw + c * 128 + ((g * 16) ^ sw));
        pa[1] = *(const bf16x8*)(pw + c * 128 + ((64 + g * 16) ^ sw));
      }
      // ---- O += P V  (B-fragments from vl, mirror of QK^T) ----
      __builtin_amdgcn_s_setprio(1);
#pragma unroll
      for (int ni = 0; ni < 4; ni++) {
        const int row = ni * 16 + c;
        const int sw  = (row & 7) << 4;
        const bf16x8 vb0 = *(const bf16x8*)(vl + row * 128 + ((g * 16) ^ sw));
        const bf16x8 vb1 = *(const bf16x8*)(vl + row * 128 + ((64 + g * 16) ^ sw));
        o[ni] = __builtin_amdgcn_mfma_f32_16x16x32_bf16(pa[0], vb0, o[ni], 0, 0, 0);
        o[ni] = __builtin_amdgcn_mfma_f32_16x16x32_bf16(pa[1], vb1, o[ni], 0, 0, 0);
      }
      __builtin_amdgcn_s_setprio(0);
    }

    // ---- epilogue: gather l for q=g*4+r, write O/l ----
#pragma unroll
    for (int r = 0; r < 4; r++) {
      const float lr   = __shfl(l_c, g * 4 + r);
      const float inv  = 1.f / lr;
      const int   qrow = qt * 64 + w * 16 + g * 4 + r;
#pragma unroll
      for (int ni = 0; ni < 4; ni++) {
        const size_t off = (size_t)(qrow * 4 + n) * E + h * 64 + ni * 16 + c;
        out[off] = (__bf16)(o[ni][r] * inv);
      }
    }
  }
}

// =====================================================================
extern "C" void kernel_launch(void* const* d_in, const int* in_sizes, int n_in,
                              void* d_out, int out_size, void* d_ws, size_t ws_size,
                              hipStream_t stream) {
  const float* x    = (const float*)d_in[0];
  const float* wqkv = (const float*)d_in[1];
  const float* wout = (const float*)d_in[2];

  char* ws = (char*)d_ws;
  __bf16* x_bf    = (__bf16*)ws;                         ws += (size_t)M * E * 2;       // 16 MB
  __bf16* wqkv_bf = (__bf16*)ws;                         ws += (size_t)QKV_LD * E * 2;  //  6 MB
  __bf16* wout_bf = (__bf16*)ws;                         ws += (size_t)E * E * 2;       //  2 MB
  __bf16* qkv     = (__bf16*)ws;                         ws += (size_t)M * QKV_LD * 2;  // 48 MB
  __bf16* attno   = (__bf16*)ws;                                                        // 16 MB
  __bf16* vT      = x_bf;   // x_bf dead after QKV GEMM; reuse as vT (16 MB)
  float*  outp    = (float*)d_out;

  cvt_f32_bf16<<<(M * E / 4) / 256, 256, 0, stream>>>(x, x_bf, M * E / 4);
  cvt_f32_bf16<<<(QKV_LD * E / 4) / 256, 256, 0, stream>>>(wqkv, wqkv_bf, QKV_LD * E / 4);
  cvt_f32_bf16<<<(E * E / 4) / 256, 256, 0, stream>>>(wout, wout_bf, E * E / 4);

  gemm_bt<QKV_LD, __bf16><<<dim3(QKV_LD / 128, M / 128), 256, 0, stream>>>(x_bf, wqkv_bf, qkv);
  transpose_v<<<dim3(L / 64, NB * H), 256, 0, stream>>>(qkv, vT);
  attn_kernel<<<dim3(16, NB * H), 256, 0, stream>>>(qkv, vT, attno);
  gemm_bt<E, float><<<dim3(E / 128, M / 128), 256, 0, stream>>>(attno, wout_bf, outp);
}